// Round 4
// baseline (112.076 us; speedup 1.0000x reference)
//
#include <hip/hip_runtime.h>

// Polyphase resample up=3 down=2, N=2097152, L=129 taps, start=(L-1)/2=64.
// out[3j+0] = 3 * sum_i x[21+2j-i] * h[1+3i]   (i in [0,43))
// out[3j+1] = 3 * sum_i x[22+2j-i] * h[0+3i]
// out[3j+2] = 3 * sum_i x[22+2j-i] * h[2+3i]
// (formula verified across R0-R5, absmax 0.25)
//
// R6: restore the best-measured structure (R0 chunked, ~69.6us bench) and
// shrink its one inefficiency: 6 serial full-lgkmcnt drains per wave
// (h s_loads are SMEM = out-of-order on lgkmcnt, so every h-consuming FMA
// cluster forces lgkmcnt(0), draining the chunk's ds_reads too).
// Re-chunk 5x8+3 -> 16+16+11: same do_chunk code, 3 drains instead of 6.
//   <16,6>@0 : D=30 (D>>3=4? no: 30>>3=3, R=6), window 23 words
//   <16,6>@16: D=14 (1,6), window 23 words
//   <11,3>@32: D=3  (0,3), window 18 words
// Max live even with full hoist ~90 VGPR < 128 cap from launch_bounds(256,4).
// R3/R4 lesson: the earlier spill was runtime-indexed-array demotion from a
// failed 43-tap unroll, not a register-budget issue; all indices here are
// compile-time (same as the verified U=8 instantiation).

#define N_SIG   2097152
#define L_FILT  129
#define NTAPS   43
#define G       4            // output groups per thread (12 outputs)
#define BLK     256
#define GROUPS_PER_BLK (BLK * G)             // 1024 groups -> 3072 outputs/block
#define TILE_Q  2112                         // logical tile words (covers q in [0,2093))
#define TILE_P  (TILE_Q + TILE_Q / 8)        // 2376: pad 1 word per 8 -> lane
                                             // stride 9 (odd) -> conflict-free

// One tap-chunk of U taps starting at compile-time-residue base. D = 45-(i0+U-1);
// R = D&7 must be a compile-time constant so the per-k pad offsets ((R+k)>>3)
// are immediates. (Verbatim from the verified R0 kernel.)
template <int U, int R>
__device__ __forceinline__ void do_chunk(const float* __restrict__ xs,
                                         const float* __restrict__ h,
                                         int i0, int tid, float (&acc)[3 * G]) {
    const int D = 45 - (i0 + U - 1);          // window base in d-space (runtime)
    const int pb = 9 * tid + 9 * (D >> 3) + R; // padded word addr of window[0]
    float wz[U + 7];                           // window: d in [D, D+U+6]
#pragma unroll
    for (int k = 0; k < U + 7; ++k)
        wz[k] = xs[pb + k + ((R + k) >> 3)];   // const offsets, stride-9 lanes
#pragma unroll
    for (int u = 0; u < U; ++u) {
        // wave-uniform indices -> scalar loads, SGPR operands in the FMAs
        const float h0 = h[3 * (i0 + u) + 0];
        const float h1 = h[3 * (i0 + u) + 1];
        const float h2 = h[3 * (i0 + u) + 2];
#pragma unroll
        for (int g = 0; g < G; ++g) {
            const float xa = wz[(U - 1 - u) + 2 * g];      // x[21+2j-i]
            const float xb = wz[(U - 1 - u) + 2 * g + 1];  // x[22+2j-i]
            acc[3 * g + 0] += xa * h1;
            acc[3 * g + 1] += xb * h0;
            acc[3 * g + 2] += xb * h2;
        }
    }
}

__global__ __launch_bounds__(BLK, 4) void poly_kernel(
    const float* __restrict__ x, const float* __restrict__ h,
    float* __restrict__ out, int n_out)
{
    __shared__ float xs[TILE_P];

    const int tid = threadIdx.x;
    const int b   = blockIdx.x;

    // Tile base: local group jl uses x[2*GPB*b + {21,22} + 2*jl - i];
    // tb = 2048b - 24 puts needed words at q = 45 + 2*jl - i in [3, 2093).
    const int tb = 2 * GROUPS_PER_BLK * b - 24;

    // Coalesced staging with zero-pad at edges. Logical word q lives at
    // p = q + (q>>3); a float4 at q%8 in {0,4} never straddles a pad.
    for (int q4 = tid; q4 < TILE_Q / 4; q4 += BLK) {
        const int gx = tb + 4 * q4;
        float4 v;
        if (gx >= 0 && gx + 3 < N_SIG) {
            v = *(const float4*)(x + gx);
        } else {
            v.x = (gx     >= 0 && gx     < N_SIG) ? x[gx]     : 0.0f;
            v.y = (gx + 1 >= 0 && gx + 1 < N_SIG) ? x[gx + 1] : 0.0f;
            v.z = (gx + 2 >= 0 && gx + 2 < N_SIG) ? x[gx + 2] : 0.0f;
            v.w = (gx + 3 >= 0 && gx + 3 < N_SIG) ? x[gx + 3] : 0.0f;
        }
        const int q = 4 * q4;
        const int p = q + (q >> 3);
        xs[p + 0] = v.x; xs[p + 1] = v.y; xs[p + 2] = v.z; xs[p + 3] = v.w;
    }
    __syncthreads();

    float acc[3 * G];
#pragma unroll
    for (int k = 0; k < 3 * G; ++k) acc[k] = 0.0f;

    // Three chunks, three lgkm dependency heads per wave (was six).
    do_chunk<16, 6>(xs, h, 0,  tid, acc);
    do_chunk<16, 6>(xs, h, 16, tid, acc);
    do_chunk<11, 3>(xs, h, 32, tid, acc);

    // 12 contiguous outputs per thread (16B-aligned); fold the up=3 gain here.
    const int ob = 3 * GROUPS_PER_BLK * b + 3 * G * tid;
#pragma unroll
    for (int k = 0; k < 3; ++k) {
        if (ob + 4 * k + 3 < n_out) {
            *(float4*)(out + ob + 4 * k) =
                make_float4(3.0f * acc[4 * k + 0], 3.0f * acc[4 * k + 1],
                            3.0f * acc[4 * k + 2], 3.0f * acc[4 * k + 3]);
        }
    }
}

extern "C" void kernel_launch(void* const* d_in, const int* in_sizes, int n_in,
                              void* d_out, int out_size, void* d_ws, size_t ws_size,
                              hipStream_t stream) {
    const float* x = (const float*)d_in[0];
    const float* h = (const float*)d_in[1];
    float* out = (float*)d_out;
    const int blocks = (out_size + 3 * GROUPS_PER_BLK - 1) / (3 * GROUPS_PER_BLK);
    poly_kernel<<<blocks, BLK, 0, stream>>>(x, h, out, out_size);
}

// Round 5
// 70.354 us; speedup vs baseline: 1.5930x; 1.5930x over previous
//
#include <hip/hip_runtime.h>

// Polyphase resample up=3 down=2, N=2097152, L=129 taps, start=(L-1)/2=64.
// out[3j+0] = 3 * sum_i x[21+2j-i] * h[1+3i]   (i in [0,43))
// out[3j+1] = 3 * sum_i x[22+2j-i] * h[0+3i]
// out[3j+2] = 3 * sum_i x[22+2j-i] * h[2+3i]
// (formula verified across R0-R6, absmax 0.25)
//
// R7 post-mortem of R6: dropping the rolled loop let the scheduler hoist
// all three chunks' ds_reads across each other (64 window words live),
// blowing the 64-VGPR occupancy target -> scratch (FETCH 71MB/WRITE 88MB).
// Same failure as R3 and the original R2. COMPILER LAW for this kernel:
// chunk bodies must sit behind an opaque #pragma unroll 1 backedge, or
// their LDS reads get hoisted and spilled.
// This round: R0's exact mechanism (rolled loop, runtime i0) with the R6
// re-chunk applied INSIDE it: 2 iterations of U=16 (+ tail U=11) instead
// of 5 of U=8 (+ tail U=3). 3 lgkm drains/wave instead of 6, and each
// drain is hidden behind a 192-FMA body (384cy) instead of 96 (192cy).
// Per-iter live set: wz[23]+acc[12]+addr ~45 VGPR < 64 budget.

#define N_SIG   2097152
#define L_FILT  129
#define NTAPS   43
#define G       4            // output groups per thread (12 outputs)
#define BLK     256
#define GROUPS_PER_BLK (BLK * G)             // 1024 groups -> 3072 outputs/block
#define TILE_Q  2112                         // logical tile words (covers q in [0,2093))
#define TILE_P  (TILE_Q + TILE_Q / 8)        // 2376: pad 1 word per 8 -> lane
                                             // stride 9 (odd) -> conflict-free

// One tap-chunk of U taps starting at runtime i0 (i0+U-1 determines window
// base D = 45-(i0+U-1); R = D&7 must be a compile-time constant so the
// per-k pad offsets ((R+k)>>3) are immediates). Verbatim from R0.
template <int U, int R>
__device__ __forceinline__ void do_chunk(const float* __restrict__ xs,
                                         const float* __restrict__ h,
                                         int i0, int tid, float (&acc)[3 * G]) {
    const int D = 45 - (i0 + U - 1);          // window base in d-space (runtime)
    const int pb = 9 * tid + 9 * (D >> 3) + R; // padded word addr of window[0]
    float wz[U + 7];                           // window: d in [D, D+U+6]
#pragma unroll
    for (int k = 0; k < U + 7; ++k)
        wz[k] = xs[pb + k + ((R + k) >> 3)];   // const offsets, stride-9 lanes
#pragma unroll
    for (int u = 0; u < U; ++u) {
        // wave-uniform indices -> scalar loads, SGPR operands in the FMAs
        const float h0 = h[3 * (i0 + u) + 0];
        const float h1 = h[3 * (i0 + u) + 1];
        const float h2 = h[3 * (i0 + u) + 2];
#pragma unroll
        for (int g = 0; g < G; ++g) {
            const float xa = wz[(U - 1 - u) + 2 * g];      // x[21+2j-i]
            const float xb = wz[(U - 1 - u) + 2 * g + 1];  // x[22+2j-i]
            acc[3 * g + 0] += xa * h1;
            acc[3 * g + 1] += xb * h0;
            acc[3 * g + 2] += xb * h2;
        }
    }
}

__global__ __launch_bounds__(BLK, 4) void poly_kernel(
    const float* __restrict__ x, const float* __restrict__ h,
    float* __restrict__ out, int n_out)
{
    __shared__ float xs[TILE_P];

    const int tid = threadIdx.x;
    const int b   = blockIdx.x;

    // Tile base: local group jl uses x[2*GPB*b + {21,22} + 2*jl - i];
    // tb = 2048b - 24 puts needed words at q = 45 + 2*jl - i in [3, 2093).
    const int tb = 2 * GROUPS_PER_BLK * b - 24;

    // Coalesced staging with zero-pad at edges. Logical word q lives at
    // p = q + (q>>3); a float4 at q%8 in {0,4} never straddles a pad.
    for (int q4 = tid; q4 < TILE_Q / 4; q4 += BLK) {
        const int gx = tb + 4 * q4;
        float4 v;
        if (gx >= 0 && gx + 3 < N_SIG) {
            v = *(const float4*)(x + gx);
        } else {
            v.x = (gx     >= 0 && gx     < N_SIG) ? x[gx]     : 0.0f;
            v.y = (gx + 1 >= 0 && gx + 1 < N_SIG) ? x[gx + 1] : 0.0f;
            v.z = (gx + 2 >= 0 && gx + 2 < N_SIG) ? x[gx + 2] : 0.0f;
            v.w = (gx + 3 >= 0 && gx + 3 < N_SIG) ? x[gx + 3] : 0.0f;
        }
        const int q = 4 * q4;
        const int p = q + (q >> 3);
        xs[p + 0] = v.x; xs[p + 1] = v.y; xs[p + 2] = v.z; xs[p + 3] = v.w;
    }
    __syncthreads();

    float acc[3 * G];
#pragma unroll
    for (int k = 0; k < 3 * G; ++k) acc[k] = 0.0f;

    // 2 chunks of 16 taps (D = 30-i0, D&7 == 6 for both) + remainder of 11
    // (D = 3). Rolled loop: opaque backedge blocks cross-chunk hoisting.
#pragma unroll 1
    for (int i0 = 0; i0 < 32; i0 += 16)
        do_chunk<16, 6>(xs, h, i0, tid, acc);
    do_chunk<11, 3>(xs, h, 32, tid, acc);

    // 12 contiguous outputs per thread (16B-aligned); fold the up=3 gain here.
    const int ob = 3 * GROUPS_PER_BLK * b + 3 * G * tid;
#pragma unroll
    for (int k = 0; k < 3; ++k) {
        if (ob + 4 * k + 3 < n_out) {
            *(float4*)(out + ob + 4 * k) =
                make_float4(3.0f * acc[4 * k + 0], 3.0f * acc[4 * k + 1],
                            3.0f * acc[4 * k + 2], 3.0f * acc[4 * k + 3]);
        }
    }
}

extern "C" void kernel_launch(void* const* d_in, const int* in_sizes, int n_in,
                              void* d_out, int out_size, void* d_ws, size_t ws_size,
                              hipStream_t stream) {
    const float* x = (const float*)d_in[0];
    const float* h = (const float*)d_in[1];
    float* out = (float*)d_out;
    const int blocks = (out_size + 3 * GROUPS_PER_BLK - 1) / (3 * GROUPS_PER_BLK);
    poly_kernel<<<blocks, BLK, 0, stream>>>(x, h, out, out_size);
}